// Round 12
// baseline (303.060 us; speedup 1.0000x reference)
//
#include <hip/hip_runtime.h>
#include <hip/hip_bf16.h>
#include <math.h>

// Problem constants
constexpr int B = 8, S = 512, T = 256, D = 768, H = 12, HID = 3072;
constexpr int V = 50257, O = 64, HD = 64;

typedef short bf16x8 __attribute__((ext_vector_type(8)));
typedef float f32x4 __attribute__((ext_vector_type(4)));

__device__ __forceinline__ float b2f(unsigned short u) {
  union { float f; unsigned v; } x; x.v = ((unsigned)u) << 16; return x.f;
}
__device__ __forceinline__ unsigned short f2b(float f) {
  __hip_bfloat16 h = __float2bfloat16(f);
  return *(unsigned short*)&h;
}

__device__ __forceinline__ void async16(const void* g, void* l) {
  __builtin_amdgcn_global_load_lds(
      (const __attribute__((address_space(1))) void*)g,
      (__attribute__((address_space(3))) void*)l, 16, 0, 0);
}

// ---------------------------------------------------------------------------
// Fused fp32->bf16 conversion (7 regions) + w_eff computation (4 extra blocks)
// ---------------------------------------------------------------------------
constexpr int CH0 = B * T * D / 8;
constexpr int CH1 = CH0 + B * S * D / 8;
constexpr int CH2 = CH1 + HID * D / 8;
constexpr int CH3 = CH2 + D * D / 8;
constexpr int CH4 = CH3 + D * D / 8;
constexpr int CH5 = CH4 + D * D / 8;
constexpr int CH6 = CH5 + O * HID / 8;   // total cvt chunks (divisible by 256)

__global__ void cvt_weff_kernel(
    const float* __restrict__ dec, const float* __restrict__ enc,
    const float* __restrict__ W1, const float* __restrict__ Wq,
    const float* __restrict__ Wk, const float* __restrict__ Wv,
    const float* __restrict__ W2, const float* __restrict__ Wo,
    const float* __restrict__ bo, const float* __restrict__ cw,
    const float* __restrict__ cb,
    __hip_bfloat16* __restrict__ decb, __hip_bfloat16* __restrict__ encb,
    __hip_bfloat16* __restrict__ WA, __hip_bfloat16* __restrict__ WB,
    __hip_bfloat16* __restrict__ W2b, float* __restrict__ weff) {
  int i = blockIdx.x * blockDim.x + threadIdx.x;
  if (i >= CH6) {
    int j = i - CH6;
    if (j < D) {
      float acc = 0.f;
      for (int o = 0; o < D; ++o) acc += Wo[(size_t)o * D + j] * cw[o];
      weff[j] = acc;
    } else if (j == D) {
      float acc = cb[0];
      for (int o = 0; o < D; ++o) acc += bo[o] * cw[o];
      weff[D] = acc;
    }
    return;
  }
  const float* src;
  __hip_bfloat16* dst;
  int j;
  if (i < CH0)      { src = dec; dst = decb;                 j = i; }
  else if (i < CH1) { src = enc; dst = encb;                 j = i - CH0; }
  else if (i < CH2) { src = W1;  dst = WA;                   j = i - CH1; }
  else if (i < CH3) { src = Wq;  dst = WA + (size_t)HID * D; j = i - CH2; }
  else if (i < CH4) { src = Wk;  dst = WB;                   j = i - CH3; }
  else if (i < CH5) { src = Wv;  dst = WB + (size_t)D * D;   j = i - CH4; }
  else              { src = W2;  dst = W2b;                  j = i - CH5; }
  size_t e = (size_t)j * 8;
  float4 v0 = *(const float4*)&src[e];
  float4 v1 = *(const float4*)&src[e + 4];
  ushort4 o0, o1;
  o0.x = f2b(v0.x); o0.y = f2b(v0.y); o0.z = f2b(v0.z); o0.w = f2b(v0.w);
  o1.x = f2b(v1.x); o1.y = f2b(v1.y); o1.z = f2b(v1.z); o1.w = f2b(v1.w);
  *(ushort4*)&dst[e] = o0;
  *(ushort4*)&dst[e + 4] = o1;
}

// ---------------------------------------------------------------------------
// Shared GEMM body (BM=128, BN in {64,128}, BK=32, 256 thr).
// MODE 1: FFN1(relu)+Q split epilogue. MODE 2: K + V(transposed) epilogue.
// MODE 3: raw fp32 partial (split-K).
// ---------------------------------------------------------------------------
template <int BN, int MODE>
__device__ __forceinline__ void gemm_body(
    const __hip_bfloat16* __restrict__ A, const __hip_bfloat16* __restrict__ W,
    const float* __restrict__ bias0, const float* __restrict__ bias1,
    float* __restrict__ Cf, __hip_bfloat16* __restrict__ out0,
    __hip_bfloat16* __restrict__ out1, int M, int N, int K,
    int bx, int by, int kbeg, int kend,
    __hip_bfloat16* Als, __hip_bfloat16* Bls) {
  constexpr int BK = 32;
  constexpr int WTN = BN / 2;
  constexpr int NFRAG = WTN / 16;
  const int tid = threadIdx.x;
  const int lane = tid & 63, wid = tid >> 6;
  const int wm = wid >> 1, wn = wid & 1;
  const int row0 = by * 128, col0 = bx * BN;
  const int lr = lane & 15;
  const int ko = (lane >> 4) * 8;

  f32x4 acc[4][NFRAG] = {};

  for (int k0 = kbeg; k0 < kend; k0 += BK) {
#pragma unroll
    for (int c = 0; c < 2; ++c) {
      int j = tid + c * 256;
      int r = j >> 2, col = (j & 3) * 8;
      async16(&A[(size_t)(row0 + r) * K + k0 + col], (void*)&Als[j * 8]);
    }
#pragma unroll
    for (int c = 0; c < BN / 64; ++c) {
      int j = tid + c * 256;
      int r = j >> 2, col = (j & 3) * 8;
      async16(&W[(size_t)(col0 + r) * K + k0 + col], (void*)&Bls[j * 8]);
    }
    __syncthreads();

    bf16x8 af[4], bfr[NFRAG];
#pragma unroll
    for (int mi = 0; mi < 4; ++mi)
      af[mi] = *(const bf16x8*)&Als[(wm * 64 + mi * 16 + lr) * BK + ko];
#pragma unroll
    for (int ni = 0; ni < NFRAG; ++ni)
      bfr[ni] = *(const bf16x8*)&Bls[(wn * WTN + ni * 16 + lr) * BK + ko];
#pragma unroll
    for (int mi = 0; mi < 4; ++mi)
#pragma unroll
      for (int ni = 0; ni < NFRAG; ++ni)
        acc[mi][ni] = __builtin_amdgcn_mfma_f32_16x16x32_bf16(
            af[mi], bfr[ni], acc[mi][ni], 0, 0, 0);
    __syncthreads();
  }

#pragma unroll
  for (int mi = 0; mi < 4; ++mi) {
    int rbase = row0 + wm * 64 + mi * 16 + (lane >> 4) * 4;
#pragma unroll
    for (int ni = 0; ni < NFRAG; ++ni) {
      int c = col0 + wn * WTN + ni * 16 + lr;
#pragma unroll
      for (int r = 0; r < 4; ++r) {
        int rr = rbase + r;
        float a = acc[mi][ni][r];
        if constexpr (MODE == 1) {
          if (c < HID) {
            out0[(size_t)rr * HID + c] = __float2bfloat16(fmaxf(a + bias0[c], 0.f));
          } else {
            out1[(size_t)rr * D + (c - HID)] = __float2bfloat16(a + bias1[c - HID]);
          }
        } else if constexpr (MODE == 2) {
          if (c < D) {
            out0[(size_t)rr * D + c] = __float2bfloat16(a + bias0[c]);
          } else {
            int d = c - D;
            size_t idx = (((size_t)(rr >> 9) * D + d) << 9) | (size_t)(rr & 511);
            out1[idx] = __float2bfloat16(a + bias1[d]);
          }
        } else {
          Cf[(size_t)rr * N + c] = a;
        }
      }
    }
  }
}

// Mega launch: pure GEMM, 864 blocks, XCD-aware swizzle (864 % 8 == 0).
// XCD x gets contiguous gid chunk [x*108, (x+1)*108): 9 A-panels + all W
// per chunk -> fits 4 MB XCD L2.
constexpr int KV_BX = (2 * D) / 128;                 // 12
constexpr int KV_BLOCKS = KV_BX * (B * S / 128);     // 384
constexpr int FQ_BX = (HID + D) / 128;               // 30
constexpr int FQ_BLOCKS = FQ_BX * (B * T / 128);     // 480
constexpr int GEMM_BLOCKS = KV_BLOCKS + FQ_BLOCKS;   // 864

__global__ __launch_bounds__(256) void gemm_mega_kernel(
    const __hip_bfloat16* __restrict__ encb, const __hip_bfloat16* __restrict__ WB,
    const float* __restrict__ bk, const float* __restrict__ bv,
    __hip_bfloat16* __restrict__ kb16, __hip_bfloat16* __restrict__ vt,
    const __hip_bfloat16* __restrict__ decb, const __hip_bfloat16* __restrict__ WA,
    const float* __restrict__ b1, const float* __restrict__ bq,
    __hip_bfloat16* __restrict__ hb16, __hip_bfloat16* __restrict__ qb16) {
  __shared__ __hip_bfloat16 Als[128 * 32];
  __shared__ __hip_bfloat16 Bls[128 * 32];
  int bid = blockIdx.x;
  int gid = (bid & 7) * (GEMM_BLOCKS / 8) + (bid >> 3);  // XCD swizzle
  if (gid < KV_BLOCKS) {
    gemm_body<128, 2>(encb, WB, bk, bv, nullptr, kb16, vt,
                      B * S, 2 * D, D, gid % KV_BX, gid / KV_BX, 0, D, Als, Bls);
  } else {
    int r = gid - KV_BLOCKS;
    gemm_body<128, 1>(decb, WA, b1, bq, nullptr, hb16, qb16,
                      B * T, HID + D, D, r % FQ_BX, r / FQ_BX, 0, D, Als, Bls);
  }
}

// FFN2 split-K config
constexpr int NSPLIT = 16;
constexpr int KCH = HID / NSPLIT;  // 192
constexpr int FFN2_BLOCKS = NSPLIT * (B * T / 128);  // 256

// Attention config
constexpr int ATTN_BLOCKS = B * H * (T / 32);        // 768

// ---------------------------------------------------------------------------
// Attention body (device fn, LDS carved from arena)
// ---------------------------------------------------------------------------
__device__ void attn_body(
    const __hip_bfloat16* __restrict__ q, const __hip_bfloat16* __restrict__ k,
    const __hip_bfloat16* __restrict__ vt, const unsigned char* __restrict__ mask,
    __hip_bfloat16* __restrict__ ctx, __hip_bfloat16* __restrict__ Pg,
    int bid, char* smem) {
  constexpr int TB = 32;
  constexpr int SCP = 520;
  __hip_bfloat16* Qls = (__hip_bfloat16*)smem;             // 4 KB
  __hip_bfloat16* KVls = Qls + TB * 64;                    // 16 KB
  __hip_bfloat16* sc = KVls + 128 * 64;                    // 33.3 KB
  const int tid = threadIdx.x;
  const int lane = tid & 63, w = tid >> 6;
  const int lr = lane & 15, lg = lane >> 4;
  const int tile = bid & 7;
  const int h = (bid >> 3) % H;
  const int b = bid / (8 * H);
  const int t0 = tile * TB;

  {
    int r = tid >> 3, slot = tid & 7;
    int g = slot ^ (r & 7);
    async16(&q[((size_t)(b * T + t0 + r)) * D + h * 64 + g * 8],
            (void*)&Qls[tid * 8]);
  }

  for (int ch = 0; ch < 4; ++ch) {
    const int s0 = ch * 128;
#pragma unroll
    for (int it = 0; it < 4; ++it) {
      int c = tid + it * 256;
      int r = c >> 3, slot = c & 7;
      int g = slot ^ (r & 7);
      async16(&k[((size_t)(b * S + s0 + r)) * D + h * 64 + g * 8],
              (void*)&KVls[c * 8]);
    }
    __syncthreads();
    f32x4 acc[2][2] = {};
#pragma unroll
    for (int ks = 0; ks < 2; ++ks) {
      bf16x8 af[2], bfr[2];
#pragma unroll
      for (int mi = 0; mi < 2; ++mi) {
        int row = mi * 16 + lr;
        int slot = (4 * ks + lg) ^ (row & 7);
        af[mi] = *(const bf16x8*)&Qls[row * 64 + slot * 8];
      }
#pragma unroll
      for (int ni = 0; ni < 2; ++ni) {
        int row = w * 32 + ni * 16 + lr;
        int slot = (4 * ks + lg) ^ (row & 7);
        bfr[ni] = *(const bf16x8*)&KVls[row * 64 + slot * 8];
      }
#pragma unroll
      for (int mi = 0; mi < 2; ++mi)
#pragma unroll
        for (int ni = 0; ni < 2; ++ni)
          acc[mi][ni] = __builtin_amdgcn_mfma_f32_16x16x32_bf16(
              af[mi], bfr[ni], acc[mi][ni], 0, 0, 0);
    }
#pragma unroll
    for (int ni = 0; ni < 2; ++ni) {
      int s_local = w * 32 + ni * 16 + lr;
      bool msk = mask[b * S + s0 + s_local];
#pragma unroll
      for (int mi = 0; mi < 2; ++mi) {
        int trow = mi * 16 + lg * 4;
#pragma unroll
        for (int rg = 0; rg < 4; ++rg) {
          float val = msk ? -INFINITY : acc[mi][ni][rg] * 0.125f;
          sc[(trow + rg) * SCP + s0 + s_local] = __float2bfloat16(val);
        }
      }
    }
    __syncthreads();
  }

  unsigned short* scu = (unsigned short*)sc;
  unsigned short* pgu = (unsigned short*)Pg;
#pragma unroll
  for (int i = 0; i < 8; ++i) {
    int r = w * 8 + i;
    float x[8];
    float m = -INFINITY;
#pragma unroll
    for (int j = 0; j < 8; ++j) {
      x[j] = b2f(scu[r * SCP + j * 64 + lane]);
      m = fmaxf(m, x[j]);
    }
#pragma unroll
    for (int o = 32; o > 0; o >>= 1) m = fmaxf(m, __shfl_xor(m, o));
    float ssum = 0.f;
#pragma unroll
    for (int j = 0; j < 8; ++j) { x[j] = __expf(x[j] - m); ssum += x[j]; }
#pragma unroll
    for (int o = 32; o > 0; o >>= 1) ssum += __shfl_xor(ssum, o);
    float inv = 1.f / ssum;
#pragma unroll
    for (int j = 0; j < 8; ++j) {
      unsigned short pb = f2b(x[j] * inv);
      scu[r * SCP + j * 64 + lane] = pb;
      pgu[(((size_t)(b * H + h)) * T + t0 + r) * S + j * 64 + lane] = pb;
    }
  }
  __syncthreads();

  f32x4 accp[2] = {};
  for (int ch = 0; ch < 4; ++ch) {
    const int s0 = ch * 128;
#pragma unroll
    for (int it = 0; it < 4; ++it) {
      int c = tid + it * 256;
      int d = c >> 4, slot = c & 15;
      int g = slot ^ (d & 7);
      async16(&vt[(((size_t)(b * H + h)) * 64 + d) * S + s0 + g * 8],
              (void*)&KVls[c * 8]);
    }
    __syncthreads();
#pragma unroll
    for (int ks = 0; ks < 4; ++ks) {
      bf16x8 bfr;
      {
        int brow = w * 16 + lr;
        int slot = (4 * ks + lg) ^ (brow & 7);
        bfr = *(const bf16x8*)&KVls[brow * 128 + slot * 8];
      }
#pragma unroll
      for (int mi = 0; mi < 2; ++mi) {
        int prow = mi * 16 + lr;
        bf16x8 af = *(const bf16x8*)&sc[prow * SCP + s0 + ks * 32 + lg * 8];
        accp[mi] = __builtin_amdgcn_mfma_f32_16x16x32_bf16(af, bfr, accp[mi], 0, 0, 0);
      }
    }
    __syncthreads();
  }
#pragma unroll
  for (int mi = 0; mi < 2; ++mi) {
    int trow = mi * 16 + lg * 4;
#pragma unroll
    for (int rg = 0; rg < 4; ++rg) {
      ctx[((size_t)(b * T + t0 + trow + rg)) * D + h * 64 + w * 16 + lr] =
          __float2bfloat16(accp[mi][rg]);
    }
  }
}

// ---------------------------------------------------------------------------
// Merged FFN2 + attention launch. FFN2 first [0,256); attention [256,1024)
// with XCD swizzle (768 % 8 == 0; 256 % 8 == 0 keeps r%8 == XCD phase):
// each XCD gets 12 consecutive (b,h) groups -> K/V panels read once from HBM.
// ---------------------------------------------------------------------------
__global__ __launch_bounds__(256) void attn_ffn2_kernel(
    const __hip_bfloat16* __restrict__ q, const __hip_bfloat16* __restrict__ k,
    const __hip_bfloat16* __restrict__ vt, const unsigned char* __restrict__ mask,
    __hip_bfloat16* __restrict__ ctx, __hip_bfloat16* __restrict__ Pg,
    const __hip_bfloat16* __restrict__ hb16, const __hip_bfloat16* __restrict__ W2b,
    float* __restrict__ part) {
  __shared__ __align__(16) char smem[53760];
  int bid = blockIdx.x;
  if (bid < FFN2_BLOCKS) {
    int sp = bid & (NSPLIT - 1), mt = bid / NSPLIT;
    __hip_bfloat16* Als = (__hip_bfloat16*)smem;   // 8 KB
    __hip_bfloat16* Bls = Als + 128 * 32;          // 4 KB
    gemm_body<64, 3>(hb16, W2b, nullptr, nullptr,
                     part + (size_t)sp * (B * T) * 64, nullptr, nullptr,
                     B * T, 64, HID, 0, mt, sp * KCH, (sp + 1) * KCH, Als, Bls);
  } else {
    int r = bid - FFN2_BLOCKS;                      // 0..767
    int aid = (r & 7) * (ATTN_BLOCKS / 8) + (r >> 3);  // XCD swizzle
    attn_body(q, k, vt, mask, ctx, Pg, aid, smem);
  }
}

// ---------------------------------------------------------------------------
// Scatter v4: one block per (b,t) row. Zeroes its OWN row (normal stores ->
// L2/L3-hot), computes copy gate + ontology softmax, then atomics into the
// still-cached row. Single HBM writeback per line.
// ---------------------------------------------------------------------------
__global__ __launch_bounds__(256) void scatter4_kernel(
    const int* __restrict__ src, const int* __restrict__ onto,
    const __hip_bfloat16* __restrict__ Pg, const float* __restrict__ part,
    const float* __restrict__ b2v, const __hip_bfloat16* __restrict__ ctx,
    const float* __restrict__ weff, float* __restrict__ out) {
  const int bt = blockIdx.x;           // B*T
  const int b = bt >> 8, t = bt & (T - 1);
  const int tid = threadIdx.x;
  const int lane = tid & 63;
  float* row = out + (size_t)bt * V;

  __shared__ float red[256];
  __shared__ float onts[O];

  // phase A: zero own row (handle 16B alignment: V odd -> rows misaligned)
  {
    uintptr_t addr = (uintptr_t)row;
    int head = (int)(((16 - (addr & 15)) & 15) >> 2);
    if (tid < head) row[tid] = 0.f;
    int n4 = (V - head) >> 2;
    f32x4* row4 = (f32x4*)(row + head);
    const f32x4 z = {0.f, 0.f, 0.f, 0.f};
    for (int i = tid; i < n4; i += 256) row4[i] = z;
    int tail0 = head + (n4 << 2);
    if (tid < V - tail0) row[tail0 + tid] = 0.f;
  }

  // phase B (overlaps A's stores): copy gate dot(ctx[bt], weff)
  const unsigned short* cu = (const unsigned short*)ctx + (size_t)bt * D;
  float a = 0.f;
#pragma unroll
  for (int j = 0; j < 3; ++j) {
    int d = j * 256 + tid;
    a += b2f(cu[d]) * weff[d];
  }
  red[tid] = a;
  __syncthreads();
  for (int st = 128; st > 0; st >>= 1) {
    if (tid < st) red[tid] += red[tid + st];
    __syncthreads();
  }
  const float cpv = 1.f / (1.f + __expf(-(red[0] + weff[D])));
  __syncthreads();

  // ontology softmax (wave 0)
  if (tid < 64) {
    float x = b2v[lane];
#pragma unroll
    for (int sp = 0; sp < NSPLIT; ++sp)
      x += part[((size_t)sp * (B * T) + bt) * 64 + lane];
    float m = x;
#pragma unroll
    for (int o = 32; o > 0; o >>= 1) m = fmaxf(m, __shfl_xor(m, o));
    float e = __expf(x - m);
    float ss = e;
#pragma unroll
    for (int o = 32; o > 0; o >>= 1) ss += __shfl_xor(ss, o);
    onts[lane] = e / ss * (1.f - cpv);
  }
  __syncthreads();   // zero stores drained (barrier implies vmcnt wait)

  // phase C: atomic scatter into the L2-hot row
  const unsigned short* pg = (const unsigned short*)Pg;
#pragma unroll
  for (int jj = 0; jj < 2; ++jj) {
    int s = jj * 256 + tid;
    float sum = 0.f;
#pragma unroll
    for (int h = 0; h < H; ++h)
      sum += b2f(pg[(((size_t)(b * H + h)) * T + t) * S + s]);
    atomicAdd(&row[src[b * S + s]], sum * (1.0f / (float)H) * cpv);
  }
  if (tid < O) atomicAdd(&row[onto[tid]], onts[tid]);
}

// ---------------------------------------------------------------------------
extern "C" void kernel_launch(void* const* d_in, const int* in_sizes, int n_in,
                              void* d_out, int out_size, void* d_ws, size_t ws_size,
                              hipStream_t stream) {
  const int* src_ids = (const int*)d_in[0];
  const float* enc = (const float*)d_in[1];
  const unsigned char* mask = (const unsigned char*)d_in[2];
  const float* dec = (const float*)d_in[3];
  const int* onto_ids = (const int*)d_in[4];
  const float* Wq = (const float*)d_in[5];
  const float* bq = (const float*)d_in[6];
  const float* Wk = (const float*)d_in[7];
  const float* bk = (const float*)d_in[8];
  const float* Wv = (const float*)d_in[9];
  const float* bv = (const float*)d_in[10];
  const float* Wo = (const float*)d_in[11];
  const float* bo = (const float*)d_in[12];
  const float* copy_w = (const float*)d_in[13];
  const float* copy_b = (const float*)d_in[14];
  const float* W1 = (const float*)d_in[15];
  const float* b1 = (const float*)d_in[16];
  const float* W2 = (const float*)d_in[17];
  const float* b2 = (const float*)d_in[18];

  const int MT = B * T;   // 2048
  const int MS = B * S;   // 4096

  // bf16 workspace (persistent) — hb16 persistent (NOT aliased by Pg)
  __hip_bfloat16* wb = (__hip_bfloat16*)d_ws;
  __hip_bfloat16* qb16 = wb;    wb += (size_t)MT * D;
  __hip_bfloat16* kb16 = wb;    wb += (size_t)MS * D;
  __hip_bfloat16* vt = wb;      wb += (size_t)MS * D;        // [b][h][d][s]
  __hip_bfloat16* ctxb16 = wb;  wb += (size_t)MT * D;
  __hip_bfloat16* W2b = wb;     wb += (size_t)O * HID;
  __hip_bfloat16* WB = wb;      wb += (size_t)2 * D * D;     // [Wk; Wv]
  __hip_bfloat16* WA = wb;      wb += (size_t)(HID + D) * D; // [W1; Wq]
  __hip_bfloat16* hb16 = wb;    wb += (size_t)MT * HID;
  // transient region aliased by Pg (ONLY decb/encb — both dead after mega)
  __hip_bfloat16* Pg = wb;
  __hip_bfloat16* decb = wb;
  __hip_bfloat16* encb = decb + (size_t)MT * D;
  wb += (size_t)B * H * T * S;
  // fp32 workspace
  float* wf = (float*)wb;
  float* part = wf;             wf += (size_t)NSPLIT * MT * O;
  float* weff = wf;             wf += (size_t)(D + 1);

  float* out = (float*)d_out;

  // conversions + w_eff
  cvt_weff_kernel<<<CH6 / 256 + 4, 256, 0, stream>>>(
      dec, enc, W1, Wq, Wk, Wv, W2, Wo, bo, copy_w, copy_b,
      decb, encb, WA, WB, W2b, weff);

  // K/V + FFN1/Q projections (XCD-swizzled, pure GEMM)
  gemm_mega_kernel<<<GEMM_BLOCKS, 256, 0, stream>>>(
      encb, WB, bk, bv, kb16, vt, decb, WA, b1, bq, hb16, qb16);

  // FFN2 + attention (XCD-swizzled)
  attn_ffn2_kernel<<<FFN2_BLOCKS + ATTN_BLOCKS, 256, 0, stream>>>(
      qb16, kb16, vt, mask, ctxb16, Pg, hb16, W2b, part);

  // fused zero + copy-gate + ontology-softmax + scatter
  scatter4_kernel<<<MT, 256, 0, stream>>>(
      src_ids, onto_ids, Pg, part, b2, ctxb16, weff, out);
}

// Round 13
// 269.909 us; speedup vs baseline: 1.1228x; 1.1228x over previous
//
#include <hip/hip_runtime.h>
#include <hip/hip_bf16.h>
#include <math.h>

// Problem constants
constexpr int B = 8, S = 512, T = 256, D = 768, H = 12, HID = 3072;
constexpr int V = 50257, O = 64, HD = 64;

typedef short bf16x8 __attribute__((ext_vector_type(8)));
typedef float f32x4 __attribute__((ext_vector_type(4)));

__device__ __forceinline__ float b2f(unsigned short u) {
  union { float f; unsigned v; } x; x.v = ((unsigned)u) << 16; return x.f;
}
__device__ __forceinline__ unsigned short f2b(float f) {
  __hip_bfloat16 h = __float2bfloat16(f);
  return *(unsigned short*)&h;
}

__device__ __forceinline__ void async16(const void* g, void* l) {
  __builtin_amdgcn_global_load_lds(
      (const __attribute__((address_space(1))) void*)g,
      (__attribute__((address_space(3))) void*)l, 16, 0, 0);
}

// ---------------------------------------------------------------------------
// Fused fp32->bf16 conversion (7 regions) + w_eff computation (4 extra blocks)
// ---------------------------------------------------------------------------
constexpr int CH0 = B * T * D / 8;
constexpr int CH1 = CH0 + B * S * D / 8;
constexpr int CH2 = CH1 + HID * D / 8;
constexpr int CH3 = CH2 + D * D / 8;
constexpr int CH4 = CH3 + D * D / 8;
constexpr int CH5 = CH4 + D * D / 8;
constexpr int CH6 = CH5 + O * HID / 8;   // total cvt chunks (divisible by 256)

__global__ void cvt_weff_kernel(
    const float* __restrict__ dec, const float* __restrict__ enc,
    const float* __restrict__ W1, const float* __restrict__ Wq,
    const float* __restrict__ Wk, const float* __restrict__ Wv,
    const float* __restrict__ W2, const float* __restrict__ Wo,
    const float* __restrict__ bo, const float* __restrict__ cw,
    const float* __restrict__ cb,
    __hip_bfloat16* __restrict__ decb, __hip_bfloat16* __restrict__ encb,
    __hip_bfloat16* __restrict__ WA, __hip_bfloat16* __restrict__ WB,
    __hip_bfloat16* __restrict__ W2b, float* __restrict__ weff) {
  int i = blockIdx.x * blockDim.x + threadIdx.x;
  if (i >= CH6) {
    int j = i - CH6;
    if (j < D) {
      float acc = 0.f;
      for (int o = 0; o < D; ++o) acc += Wo[(size_t)o * D + j] * cw[o];
      weff[j] = acc;
    } else if (j == D) {
      float acc = cb[0];
      for (int o = 0; o < D; ++o) acc += bo[o] * cw[o];
      weff[D] = acc;
    }
    return;
  }
  const float* src;
  __hip_bfloat16* dst;
  int j;
  if (i < CH0)      { src = dec; dst = decb;                 j = i; }
  else if (i < CH1) { src = enc; dst = encb;                 j = i - CH0; }
  else if (i < CH2) { src = W1;  dst = WA;                   j = i - CH1; }
  else if (i < CH3) { src = Wq;  dst = WA + (size_t)HID * D; j = i - CH2; }
  else if (i < CH4) { src = Wk;  dst = WB;                   j = i - CH3; }
  else if (i < CH5) { src = Wv;  dst = WB + (size_t)D * D;   j = i - CH4; }
  else              { src = W2;  dst = W2b;                  j = i - CH5; }
  size_t e = (size_t)j * 8;
  float4 v0 = *(const float4*)&src[e];
  float4 v1 = *(const float4*)&src[e + 4];
  ushort4 o0, o1;
  o0.x = f2b(v0.x); o0.y = f2b(v0.y); o0.z = f2b(v0.z); o0.w = f2b(v0.w);
  o1.x = f2b(v1.x); o1.y = f2b(v1.y); o1.z = f2b(v1.z); o1.w = f2b(v1.w);
  *(ushort4*)&dst[e] = o0;
  *(ushort4*)&dst[e + 4] = o1;
}

// ---------------------------------------------------------------------------
// Zero helper: grid-stride over float4 range [lo4, hi4)
// ---------------------------------------------------------------------------
__device__ __forceinline__ void zero_range(float* out, long long lo4,
                                           long long hi4, int zb, int nzb) {
  f32x4* o4 = (f32x4*)out;
  const f32x4 z = {0.f, 0.f, 0.f, 0.f};
  for (long long i = lo4 + (long long)zb * 256 + threadIdx.x; i < hi4;
       i += (long long)nzb * 256)
    __builtin_nontemporal_store(z, &o4[i]);
}

constexpr long long OUT_N4 = (long long)B * T * V / 4;
constexpr long long HALF4 = OUT_N4 / 2;

// ---------------------------------------------------------------------------
// Shared GEMM body (BM=128, BN in {64,128}, BK=32, 256 thr).
// MODE 1: FFN1(relu)+Q split epilogue. MODE 2: K + V(transposed) epilogue.
// MODE 3: raw fp32 partial (split-K).
// ---------------------------------------------------------------------------
template <int BN, int MODE>
__device__ __forceinline__ void gemm_body(
    const __hip_bfloat16* __restrict__ A, const __hip_bfloat16* __restrict__ W,
    const float* __restrict__ bias0, const float* __restrict__ bias1,
    float* __restrict__ Cf, __hip_bfloat16* __restrict__ out0,
    __hip_bfloat16* __restrict__ out1, int M, int N, int K,
    int bx, int by, int kbeg, int kend,
    __hip_bfloat16* Als, __hip_bfloat16* Bls) {
  constexpr int BK = 32;
  constexpr int WTN = BN / 2;
  constexpr int NFRAG = WTN / 16;
  const int tid = threadIdx.x;
  const int lane = tid & 63, wid = tid >> 6;
  const int wm = wid >> 1, wn = wid & 1;
  const int row0 = by * 128, col0 = bx * BN;
  const int lr = lane & 15;
  const int ko = (lane >> 4) * 8;

  f32x4 acc[4][NFRAG] = {};

  for (int k0 = kbeg; k0 < kend; k0 += BK) {
#pragma unroll
    for (int c = 0; c < 2; ++c) {
      int j = tid + c * 256;
      int r = j >> 2, col = (j & 3) * 8;
      async16(&A[(size_t)(row0 + r) * K + k0 + col], (void*)&Als[j * 8]);
    }
#pragma unroll
    for (int c = 0; c < BN / 64; ++c) {
      int j = tid + c * 256;
      int r = j >> 2, col = (j & 3) * 8;
      async16(&W[(size_t)(col0 + r) * K + k0 + col], (void*)&Bls[j * 8]);
    }
    __syncthreads();

    bf16x8 af[4], bfr[NFRAG];
#pragma unroll
    for (int mi = 0; mi < 4; ++mi)
      af[mi] = *(const bf16x8*)&Als[(wm * 64 + mi * 16 + lr) * BK + ko];
#pragma unroll
    for (int ni = 0; ni < NFRAG; ++ni)
      bfr[ni] = *(const bf16x8*)&Bls[(wn * WTN + ni * 16 + lr) * BK + ko];
#pragma unroll
    for (int mi = 0; mi < 4; ++mi)
#pragma unroll
      for (int ni = 0; ni < NFRAG; ++ni)
        acc[mi][ni] = __builtin_amdgcn_mfma_f32_16x16x32_bf16(
            af[mi], bfr[ni], acc[mi][ni], 0, 0, 0);
    __syncthreads();
  }

#pragma unroll
  for (int mi = 0; mi < 4; ++mi) {
    int rbase = row0 + wm * 64 + mi * 16 + (lane >> 4) * 4;
#pragma unroll
    for (int ni = 0; ni < NFRAG; ++ni) {
      int c = col0 + wn * WTN + ni * 16 + lr;
#pragma unroll
      for (int r = 0; r < 4; ++r) {
        int rr = rbase + r;
        float a = acc[mi][ni][r];
        if constexpr (MODE == 1) {
          if (c < HID) {
            out0[(size_t)rr * HID + c] = __float2bfloat16(fmaxf(a + bias0[c], 0.f));
          } else {
            out1[(size_t)rr * D + (c - HID)] = __float2bfloat16(a + bias1[c - HID]);
          }
        } else if constexpr (MODE == 2) {
          if (c < D) {
            out0[(size_t)rr * D + c] = __float2bfloat16(a + bias0[c]);
          } else {
            int d = c - D;
            size_t idx = (((size_t)(rr >> 9) * D + d) << 9) | (size_t)(rr & 511);
            out1[idx] = __float2bfloat16(a + bias1[d]);
          }
        } else {
          Cf[(size_t)rr * N + c] = a;
        }
      }
    }
  }
}

// Mega launch, INTERLEAVED: bids [0,1728) alternate even->GEMM, odd->zero;
// tail [1728,1888) -> zero. Zero ids: odd slots 0..863, tail 864..1023.
constexpr int KV_BX = (2 * D) / 128;                 // 12
constexpr int KV_BLOCKS = KV_BX * (B * S / 128);     // 384
constexpr int FQ_BX = (HID + D) / 128;               // 30
constexpr int FQ_BLOCKS = FQ_BX * (B * T / 128);     // 480
constexpr int GEMM_BLOCKS = KV_BLOCKS + FQ_BLOCKS;   // 864
constexpr int Z1 = 1024;
constexpr int MEGA_TOTAL = 2 * GEMM_BLOCKS + (Z1 - GEMM_BLOCKS);  // 1888

__global__ __launch_bounds__(256) void gemm_mega_kernel(
    const __hip_bfloat16* __restrict__ encb, const __hip_bfloat16* __restrict__ WB,
    const float* __restrict__ bk, const float* __restrict__ bv,
    __hip_bfloat16* __restrict__ kb16, __hip_bfloat16* __restrict__ vt,
    const __hip_bfloat16* __restrict__ decb, const __hip_bfloat16* __restrict__ WA,
    const float* __restrict__ b1, const float* __restrict__ bq,
    __hip_bfloat16* __restrict__ hb16, __hip_bfloat16* __restrict__ qb16,
    float* __restrict__ out) {
  __shared__ __hip_bfloat16 Als[128 * 32];
  __shared__ __hip_bfloat16 Bls[128 * 32];
  int bid = blockIdx.x;
  int gid = -1, zid = -1;
  if (bid < 2 * GEMM_BLOCKS) {
    if ((bid & 1) == 0) gid = bid >> 1;
    else zid = bid >> 1;
  } else {
    zid = GEMM_BLOCKS + (bid - 2 * GEMM_BLOCKS);
  }
  if (gid >= 0) {
    if (gid < KV_BLOCKS) {
      gemm_body<128, 2>(encb, WB, bk, bv, nullptr, kb16, vt,
                        B * S, 2 * D, D, gid % KV_BX, gid / KV_BX, 0, D, Als, Bls);
    } else {
      int r = gid - KV_BLOCKS;
      gemm_body<128, 1>(decb, WA, b1, bq, nullptr, hb16, qb16,
                        B * T, HID + D, D, r % FQ_BX, r / FQ_BX, 0, D, Als, Bls);
    }
  } else {
    zero_range(out, 0, HALF4, zid, Z1);
  }
}

// FFN2 split-K config
constexpr int NSPLIT = 16;
constexpr int KCH = HID / NSPLIT;  // 192
constexpr int FFN2_BLOCKS = NSPLIT * (B * T / 128);  // 256

// Attention config
constexpr int ATTN_BLOCKS = B * H * (T / 32);        // 768
constexpr int Z2 = 1024;
constexpr int AF_TOTAL = 2048;

// ---------------------------------------------------------------------------
// Attention body v2: 64-s chunks (KVls 8 KB instead of 16 KB).
// Arena = 4 KB Q + 8 KB KV + 33.28 KB sc = 45.57 KB -> 3 blocks/CU (was 2).
// ---------------------------------------------------------------------------
__device__ void attn_body(
    const __hip_bfloat16* __restrict__ q, const __hip_bfloat16* __restrict__ k,
    const __hip_bfloat16* __restrict__ vt, const unsigned char* __restrict__ mask,
    __hip_bfloat16* __restrict__ ctx, __hip_bfloat16* __restrict__ Pg,
    int bid, char* smem) {
  constexpr int TB = 32;
  constexpr int SCP = 520;
  __hip_bfloat16* Qls = (__hip_bfloat16*)smem;             // 4 KB
  __hip_bfloat16* KVls = Qls + TB * 64;                    // 8 KB: [64][64]
  __hip_bfloat16* sc = KVls + 64 * 64;                     // 33.28 KB
  const int tid = threadIdx.x;
  const int lane = tid & 63, w = tid >> 6;
  const int lr = lane & 15, lg = lane >> 4;
  const int tile = bid & 7;
  const int h = (bid >> 3) % H;
  const int b = bid / (8 * H);
  const int t0 = tile * TB;

  // stage Q (32x64): 256 chunks of 16B, source slot pre-swizzled
  {
    int r = tid >> 3, slot = tid & 7;
    int g = slot ^ (r & 7);
    async16(&q[((size_t)(b * T + t0 + r)) * D + h * 64 + g * 8],
            (void*)&Qls[tid * 8]);
  }

  // ---- QK^T: 8 chunks of 64 s ----
  for (int ch = 0; ch < 8; ++ch) {
    const int s0 = ch * 64;
#pragma unroll
    for (int it = 0; it < 2; ++it) {
      int c = tid + it * 256;
      int r = c >> 3, slot = c & 7;
      int g = slot ^ (r & 7);
      async16(&k[((size_t)(b * S + s0 + r)) * D + h * 64 + g * 8],
              (void*)&KVls[c * 8]);
    }
    __syncthreads();
    f32x4 acc[2] = {};
#pragma unroll
    for (int ks = 0; ks < 2; ++ks) {
      bf16x8 af[2], bfr;
#pragma unroll
      for (int mi = 0; mi < 2; ++mi) {
        int row = mi * 16 + lr;
        int slot = (4 * ks + lg) ^ (row & 7);
        af[mi] = *(const bf16x8*)&Qls[row * 64 + slot * 8];
      }
      {
        int row = w * 16 + lr;                     // s_local row of K chunk
        int slot = (4 * ks + lg) ^ (row & 7);
        bfr = *(const bf16x8*)&KVls[row * 64 + slot * 8];
      }
#pragma unroll
      for (int mi = 0; mi < 2; ++mi)
        acc[mi] = __builtin_amdgcn_mfma_f32_16x16x32_bf16(af[mi], bfr, acc[mi], 0, 0, 0);
    }
    // scale + mask + store scores (bf16) to sc
    {
      int s_local = w * 16 + lr;
      bool msk = mask[b * S + s0 + s_local];
#pragma unroll
      for (int mi = 0; mi < 2; ++mi) {
        int trow = mi * 16 + lg * 4;
#pragma unroll
        for (int rg = 0; rg < 4; ++rg) {
          float val = msk ? -INFINITY : acc[mi][rg] * 0.125f;
          sc[(trow + rg) * SCP + s0 + s_local] = __float2bfloat16(val);
        }
      }
    }
    __syncthreads();
  }

  // ---- softmax: wave w handles rows w*8 .. w*8+7 ----
  unsigned short* scu = (unsigned short*)sc;
  unsigned short* pgu = (unsigned short*)Pg;
#pragma unroll
  for (int i = 0; i < 8; ++i) {
    int r = w * 8 + i;
    float x[8];
    float m = -INFINITY;
#pragma unroll
    for (int j = 0; j < 8; ++j) {
      x[j] = b2f(scu[r * SCP + j * 64 + lane]);
      m = fmaxf(m, x[j]);
    }
#pragma unroll
    for (int o = 32; o > 0; o >>= 1) m = fmaxf(m, __shfl_xor(m, o));
    float ssum = 0.f;
#pragma unroll
    for (int j = 0; j < 8; ++j) { x[j] = __expf(x[j] - m); ssum += x[j]; }
#pragma unroll
    for (int o = 32; o > 0; o >>= 1) ssum += __shfl_xor(ssum, o);
    float inv = 1.f / ssum;
#pragma unroll
    for (int j = 0; j < 8; ++j) {
      unsigned short pb = f2b(x[j] * inv);
      scu[r * SCP + j * 64 + lane] = pb;
      pgu[(((size_t)(b * H + h)) * T + t0 + r) * S + j * 64 + lane] = pb;
    }
  }
  __syncthreads();

  // ---- PV: 8 chunks of 64 s; KVls = Vt chunk [64 d][64 s] ----
  f32x4 accp[2] = {};
  for (int ch = 0; ch < 8; ++ch) {
    const int s0 = ch * 64;
#pragma unroll
    for (int it = 0; it < 2; ++it) {
      int c = tid + it * 256;
      int d = c >> 3, slot = c & 7;
      int g = slot ^ (d & 7);
      async16(&vt[(((size_t)(b * H + h)) * 64 + d) * S + s0 + g * 8],
              (void*)&KVls[c * 8]);
    }
    __syncthreads();
#pragma unroll
    for (int ks = 0; ks < 2; ++ks) {
      bf16x8 bfr;
      {
        int brow = w * 16 + lr;                    // d row
        int slot = (4 * ks + lg) ^ (brow & 7);
        bfr = *(const bf16x8*)&KVls[brow * 64 + slot * 8];
      }
#pragma unroll
      for (int mi = 0; mi < 2; ++mi) {
        int prow = mi * 16 + lr;
        bf16x8 af = *(const bf16x8*)&sc[prow * SCP + s0 + ks * 32 + lg * 8];
        accp[mi] = __builtin_amdgcn_mfma_f32_16x16x32_bf16(af, bfr, accp[mi], 0, 0, 0);
      }
    }
    __syncthreads();
  }
  // epilogue: ctx[b*T + t][h*64 + d]
#pragma unroll
  for (int mi = 0; mi < 2; ++mi) {
    int trow = mi * 16 + lg * 4;
#pragma unroll
    for (int rg = 0; rg < 4; ++rg) {
      ctx[((size_t)(b * T + t0 + trow + rg)) * D + h * 64 + w * 16 + lr] =
          __float2bfloat16(accp[mi][rg]);
    }
  }
}

// ---------------------------------------------------------------------------
// Merged attention + FFN2 + zero launch, interleaved dispatch order
// bids [0,1536): even -> attn(bid/2); odd o=bid/2: o<256 -> ffn2(o),
//                else zero(o-256).  [1536,2048): zero(512+...)
// ---------------------------------------------------------------------------
__global__ __launch_bounds__(256) void attn_ffn2_kernel(
    const __hip_bfloat16* __restrict__ q, const __hip_bfloat16* __restrict__ k,
    const __hip_bfloat16* __restrict__ vt, const unsigned char* __restrict__ mask,
    __hip_bfloat16* __restrict__ ctx, __hip_bfloat16* __restrict__ Pg,
    const __hip_bfloat16* __restrict__ hb16, const __hip_bfloat16* __restrict__ W2b,
    float* __restrict__ part, float* __restrict__ out) {
  __shared__ __align__(16) char smem[45568];   // 45.57 KB -> 3 blocks/CU
  int bid = blockIdx.x;
  if (bid < 2 * ATTN_BLOCKS) {
    if ((bid & 1) == 0) {
      attn_body(q, k, vt, mask, ctx, Pg, bid >> 1, smem);
    } else {
      int o = bid >> 1;
      if (o < FFN2_BLOCKS) {
        int sp = o & (NSPLIT - 1), mt = o / NSPLIT;
        __hip_bfloat16* Als = (__hip_bfloat16*)smem;   // 8 KB
        __hip_bfloat16* Bls = Als + 128 * 32;          // 4 KB
        gemm_body<64, 3>(hb16, W2b, nullptr, nullptr,
                         part + (size_t)sp * (B * T) * 64, nullptr, nullptr,
                         B * T, 64, HID, 0, mt, sp * KCH, (sp + 1) * KCH, Als, Bls);
      } else {
        zero_range(out, HALF4, OUT_N4, o - FFN2_BLOCKS, Z2);  // ids 0..511
      }
    }
  } else {
    zero_range(out, HALF4, OUT_N4, 512 + (bid - 2 * ATTN_BLOCKS), Z2);  // 512..1023
  }
}

// ---------------------------------------------------------------------------
// Scatter v3: one block per (b,t) row; computes copy gate + ontology softmax
// locally, then atomically scatters (rows pre-zeroed by earlier launches).
// ---------------------------------------------------------------------------
__global__ __launch_bounds__(256) void scatter3_kernel(
    const int* __restrict__ src, const int* __restrict__ onto,
    const __hip_bfloat16* __restrict__ Pg, const float* __restrict__ part,
    const float* __restrict__ b2v, const __hip_bfloat16* __restrict__ ctx,
    const float* __restrict__ weff, float* __restrict__ out) {
  const int bt = blockIdx.x;           // B*T
  const int b = bt >> 8, t = bt & (T - 1);
  const int tid = threadIdx.x;
  const int lane = tid & 63;
  float* row = out + (size_t)bt * V;

  __shared__ float red[256];
  __shared__ float onts[O];

  const unsigned short* cu = (const unsigned short*)ctx + (size_t)bt * D;
  float a = 0.f;
#pragma unroll
  for (int j = 0; j < 3; ++j) {
    int d = j * 256 + tid;
    a += b2f(cu[d]) * weff[d];
  }
  red[tid] = a;
  __syncthreads();
  for (int st = 128; st > 0; st >>= 1) {
    if (tid < st) red[tid] += red[tid + st];
    __syncthreads();
  }
  const float cpv = 1.f / (1.f + __expf(-(red[0] + weff[D])));
  __syncthreads();

  if (tid < 64) {
    float x = b2v[lane];
#pragma unroll
    for (int sp = 0; sp < NSPLIT; ++sp)
      x += part[((size_t)sp * (B * T) + bt) * 64 + lane];
    float m = x;
#pragma unroll
    for (int o = 32; o > 0; o >>= 1) m = fmaxf(m, __shfl_xor(m, o));
    float e = __expf(x - m);
    float ss = e;
#pragma unroll
    for (int o = 32; o > 0; o >>= 1) ss += __shfl_xor(ss, o);
    onts[lane] = e / ss * (1.f - cpv);
  }
  __syncthreads();

  const unsigned short* pg = (const unsigned short*)Pg;
#pragma unroll
  for (int jj = 0; jj < 2; ++jj) {
    int s = jj * 256 + tid;
    float sum = 0.f;
#pragma unroll
    for (int h = 0; h < H; ++h)
      sum += b2f(pg[(((size_t)(b * H + h)) * T + t) * S + s]);
    atomicAdd(&row[src[b * S + s]], sum * (1.0f / (float)H) * cpv);
  }
  if (tid < O) atomicAdd(&row[onto[tid]], onts[tid]);
}

// ---------------------------------------------------------------------------
extern "C" void kernel_launch(void* const* d_in, const int* in_sizes, int n_in,
                              void* d_out, int out_size, void* d_ws, size_t ws_size,
                              hipStream_t stream) {
  const int* src_ids = (const int*)d_in[0];
  const float* enc = (const float*)d_in[1];
  const unsigned char* mask = (const unsigned char*)d_in[2];
  const float* dec = (const float*)d_in[3];
  const int* onto_ids = (const int*)d_in[4];
  const float* Wq = (const float*)d_in[5];
  const float* bq = (const float*)d_in[6];
  const float* Wk = (const float*)d_in[7];
  const float* bk = (const float*)d_in[8];
  const float* Wv = (const float*)d_in[9];
  const float* bv = (const float*)d_in[10];
  const float* Wo = (const float*)d_in[11];
  const float* bo = (const float*)d_in[12];
  const float* copy_w = (const float*)d_in[13];
  const float* copy_b = (const float*)d_in[14];
  const float* W1 = (const float*)d_in[15];
  const float* b1 = (const float*)d_in[16];
  const float* W2 = (const float*)d_in[17];
  const float* b2 = (const float*)d_in[18];

  const int MT = B * T;   // 2048
  const int MS = B * S;   // 4096

  // bf16 workspace (persistent) — hb16 persistent (NOT aliased by Pg)
  __hip_bfloat16* wb = (__hip_bfloat16*)d_ws;
  __hip_bfloat16* qb16 = wb;    wb += (size_t)MT * D;
  __hip_bfloat16* kb16 = wb;    wb += (size_t)MS * D;
  __hip_bfloat16* vt = wb;      wb += (size_t)MS * D;        // [b][h][d][s]
  __hip_bfloat16* ctxb16 = wb;  wb += (size_t)MT * D;
  __hip_bfloat16* W2b = wb;     wb += (size_t)O * HID;
  __hip_bfloat16* WB = wb;      wb += (size_t)2 * D * D;     // [Wk; Wv]
  __hip_bfloat16* WA = wb;      wb += (size_t)(HID + D) * D; // [W1; Wq]
  __hip_bfloat16* hb16 = wb;    wb += (size_t)MT * HID;
  // transient region aliased by Pg (ONLY decb/encb — both dead after mega)
  __hip_bfloat16* Pg = wb;
  __hip_bfloat16* decb = wb;
  __hip_bfloat16* encb = decb + (size_t)MT * D;
  wb += (size_t)B * H * T * S;
  // fp32 workspace
  float* wf = (float*)wb;
  float* part = wf;             wf += (size_t)NSPLIT * MT * O;
  float* weff = wf;             wf += (size_t)(D + 1);

  float* out = (float*)d_out;

  // conversions + w_eff
  cvt_weff_kernel<<<CH6 / 256 + 4, 256, 0, stream>>>(
      dec, enc, W1, Wq, Wk, Wv, W2, Wo, bo, copy_w, copy_b,
      decb, encb, WA, WB, W2b, weff);

  // K/V + FFN1/Q projections + zero first half (interleaved dispatch)
  gemm_mega_kernel<<<MEGA_TOTAL, 256, 0, stream>>>(
      encb, WB, bk, bv, kb16, vt, decb, WA, b1, bq, hb16, qb16, out);

  // attention + FFN2 + zero second half (interleaved dispatch)
  attn_ffn2_kernel<<<AF_TOTAL, 256, 0, stream>>>(
      qb16, kb16, vt, mask, ctxb16, Pg, hb16, W2b, part, out);

  // fused copy-gate + ontology-softmax + scatter
  scatter3_kernel<<<MT, 256, 0, stream>>>(
      src_ids, onto_ids, Pg, part, b2, ctxb16, weff, out);
}